// Round 16
// baseline (556.075 us; speedup 1.0000x reference)
//
#include <hip/hip_runtime.h>

#define N_NODES 100000
#define N_EDGES 1600000
#define N_GRAPHS 256
#define F_IN 32
#define F_HID 64
#define F_OUT 64

#define FL_BLOCKS 3125          // 12500 waves x 8 nodes = 100000
#define NXCD 8
#define DPX ((N_NODES + NXCD - 1) / NXCD)

// ---------------- CSR build ----------------
__global__ __launch_bounds__(256) void histogram_xcd(const int* __restrict__ dst,
                                                     int* __restrict__ deg) {
    int xcd = blockIdx.x & (NXCD - 1);
    int sub = blockIdx.x >> 3;
    int nsub = gridDim.x >> 3;
    int d_lo = xcd * DPX;
    int d_hi = min(d_lo + DPX, N_NODES);
    for (int e = sub * blockDim.x + threadIdx.x; e < N_EDGES; e += nsub * blockDim.x) {
        int d = __builtin_nontemporal_load(dst + e);
        if (d >= d_lo && d < d_hi) atomicAdd(&deg[d], 1);
    }
}

__global__ void scan1(const int* __restrict__ deg, int* __restrict__ end_, int* __restrict__ partials) {
    __shared__ int s[256];
    int tid = threadIdx.x;
    int i = blockIdx.x * 256 + tid;
    int v = (i < N_NODES) ? deg[i] : 0;
    s[tid] = v;
    __syncthreads();
#pragma unroll
    for (int off = 1; off < 256; off <<= 1) {
        int t = 0;
        if (tid >= off) t = s[tid - off];
        __syncthreads();
        if (tid >= off) s[tid] += t;
        __syncthreads();
    }
    if (i < N_NODES) end_[i] = s[tid];
    if (tid == 255) partials[blockIdx.x] = s[255];
}

__global__ void scan2(int* __restrict__ partials, int nb) {
    __shared__ int s[512];
    int tid = threadIdx.x;
    int v = (tid < nb) ? partials[tid] : 0;
    s[tid] = v;
    __syncthreads();
#pragma unroll
    for (int off = 1; off < 512; off <<= 1) {
        int t = 0;
        if (tid >= off) t = s[tid - off];
        __syncthreads();
        if (tid >= off) s[tid] += t;
        __syncthreads();
    }
    int excl = (tid > 0) ? s[tid - 1] : 0;
    if (tid < nb) partials[tid] = excl;
}

__global__ void scan3(const int* __restrict__ deg, int* __restrict__ end_,
                      int* __restrict__ cursor, const int* __restrict__ partials) {
    int i = blockIdx.x * 256 + threadIdx.x;
    if (i < N_NODES) {
        int e = end_[i] + partials[blockIdx.x];
        end_[i] = e;
        cursor[i] = e - deg[i];
    }
}

__global__ __launch_bounds__(256) void fill_adj_xcd(const int* __restrict__ src,
                                                    const int* __restrict__ dst,
                                                    int* __restrict__ cursor,
                                                    int* __restrict__ adj) {
    int xcd = blockIdx.x & (NXCD - 1);
    int sub = blockIdx.x >> 3;
    int nsub = gridDim.x >> 3;
    int d_lo = xcd * DPX;
    int d_hi = min(d_lo + DPX, N_NODES);
    for (int e = sub * blockDim.x + threadIdx.x; e < N_EDGES; e += nsub * blockDim.x) {
        int d = __builtin_nontemporal_load(dst + e);
        if (d >= d_lo && d < d_hi) {
            int pos = atomicAdd(&cursor[d], 1);
            adj[pos] = __builtin_nontemporal_load(src + e);
        }
    }
}

// ---------------- fused layer: gather (reg) + transform (shfl-broadcast) + pool ----------------
// Wave handles 8 consecutive nodes. Gather: lane=(r,q) column layout, float4 loads,
// xor-butterfly leaves EVERY lane holding the full agg sum for its quad q.
// Transform: per k-quad kq, broadcast agg/self quad from lane kq (4+4 shfl) and FMA
// against per-lane coalesced weight columns W[k][lane] (16 KB, L1-resident).
// No LDS, no agg round-trip through HBM.
template <int FIN, bool POOL>
__global__ __launch_bounds__(256) void fused_layer(
        const float* __restrict__ hin,
        const int* __restrict__ adj, const int* __restrict__ end_, const int* __restrict__ deg,
        const float* __restrict__ Wrel, const float* __restrict__ brel,
        const float* __restrict__ Wroot,
        float* __restrict__ hout,
        const int* __restrict__ batch,
        float* __restrict__ sums) {
    constexpr int NQ = FIN / 4;       // quads per input row: 16 (FIN=64) or 8 (FIN=32)
    constexpr int R = 64 / NQ;        // neighbor rows in flight: 4 or 8
    const int lane = threadIdx.x & 63;
    const int wid = blockIdx.x * 4 + (threadIdx.x >> 6);
    int n0 = wid * 8;
    if (n0 >= N_NODES) return;
    int n1 = min(n0 + 8, N_NODES);
    const int q = lane & (NQ - 1);
    const int r = lane / NQ;
    const float4* h4 = (const float4*)hin;
    float bb = brel[lane];

    float psum = 0.0f;
    int curg = POOL ? batch[n0] : 0;

    for (int node = n0; node < n1; ++node) {
        int e = end_[node];
        int d = deg[node];
        int s = e - d;
        float ax = 0.f, ay = 0.f, az = 0.f, aw = 0.f;
        for (int base = 0; base < d; base += 2 * R) {
            int i0 = base + r;
            int i1 = base + R + r;
            if (i0 < d) {
                int sn = adj[s + i0];
                float4 v = h4[(size_t)sn * NQ + q];
                ax += v.x; ay += v.y; az += v.z; aw += v.w;
            }
            if (i1 < d) {
                int sn = adj[s + i1];
                float4 v = h4[(size_t)sn * NQ + q];
                ax += v.x; ay += v.y; az += v.z; aw += v.w;
            }
        }
        // butterfly across the R row-groups: afterwards every lane holds the
        // complete agg quad for its q.
#pragma unroll
        for (int off = NQ; off < 64; off <<= 1) {
            ax += __shfl_xor(ax, off);
            ay += __shfl_xor(ay, off);
            az += __shfl_xor(az, off);
            aw += __shfl_xor(aw, off);
        }
        float4 xv = h4[(size_t)node * NQ + q];   // self row quad

        float o = bb;
#pragma unroll
        for (int kq = 0; kq < NQ; ++kq) {
            float a0 = __shfl(ax, kq), a1 = __shfl(ay, kq);
            float a2 = __shfl(az, kq), a3 = __shfl(aw, kq);
            float x0 = __shfl(xv.x, kq), x1 = __shfl(xv.y, kq);
            float x2 = __shfl(xv.z, kq), x3 = __shfl(xv.w, kq);
            o += a0 * Wrel[(4 * kq + 0) * 64 + lane] + a1 * Wrel[(4 * kq + 1) * 64 + lane]
               + a2 * Wrel[(4 * kq + 2) * 64 + lane] + a3 * Wrel[(4 * kq + 3) * 64 + lane];
            o += x0 * Wroot[(4 * kq + 0) * 64 + lane] + x1 * Wroot[(4 * kq + 1) * 64 + lane]
               + x2 * Wroot[(4 * kq + 2) * 64 + lane] + x3 * Wroot[(4 * kq + 3) * 64 + lane];
        }
        float hv = tanhf(o);
        if (POOL) {
            int g = batch[node];                 // wave-uniform
            if (g != curg) {
                atomicAdd(&sums[(size_t)curg * 64 + lane], psum);
                psum = 0.0f;
                curg = g;
            }
            psum += hv;
        } else {
            hout[(size_t)node * 64 + lane] = hv;
        }
    }
    if (POOL) atomicAdd(&sums[(size_t)curg * 64 + lane], psum);
}

__global__ void graph_counts(const int* __restrict__ batch, float* __restrict__ counts) {
    int g = threadIdx.x;
    if (g >= N_GRAPHS) return;
    int lo = 0, hi = N_NODES;
    while (lo < hi) { int mid = (lo + hi) >> 1; if (batch[mid] < g) lo = mid + 1; else hi = mid; }
    int start = lo;
    lo = 0; hi = N_NODES;
    while (lo < hi) { int mid = (lo + hi) >> 1; if (batch[mid] <= g) lo = mid + 1; else hi = mid; }
    counts[g] = (float)(lo - start);
}

__global__ void finalize(const float* __restrict__ sums,
                         const float* __restrict__ counts,
                         float* __restrict__ out) {
    int i = blockIdx.x * blockDim.x + threadIdx.x;
    if (i < N_GRAPHS * 64) {
        float c = counts[i >> 6];
        out[i] = sums[i] / fmaxf(c, 1.0f);
    }
}

extern "C" void kernel_launch(void* const* d_in, const int* in_sizes, int n_in,
                              void* d_out, int out_size, void* d_ws, size_t ws_size,
                              hipStream_t stream) {
    const float* x       = (const float*)d_in[0];
    const int*   ei      = (const int*)d_in[1];
    const int*   batch   = (const int*)d_in[2];
    const float* W1_rel  = (const float*)d_in[3];
    const float* b1_rel  = (const float*)d_in[4];
    const float* W1_root = (const float*)d_in[5];
    const float* W2_rel  = (const float*)d_in[6];
    const float* b2_rel  = (const float*)d_in[7];
    const float* W2_root = (const float*)d_in[8];
    float* out = (float*)d_out;

    const int* src = ei;
    const int* dst = ei + N_EDGES;

    // ---- workspace layout (bytes) ----
    char* ws = (char*)d_ws;
    int*   deg      = (int*)(ws + 0);                 // 400000
    float* sums     = (float*)(ws + 400000);          // 65536
    float* counts   = (float*)(ws + 465536);          // 1024
    // ---- zero boundary: 466560 ----
    int*   end_     = (int*)(ws + 466560);            // 400000
    int*   cursor   = (int*)(ws + 866560);            // 400000
    int*   partials = (int*)(ws + 1266560);           // 2048
    int*   adj      = (int*)(ws + 1268608);           // 6400000
    float* h1       = (float*)(ws + 7668608);         // 25600000

    hipMemsetAsync(d_ws, 0, 466560, stream);

    // ---- CSR build ----
    const int NB_NODE = (N_NODES + 255) / 256;
    histogram_xcd<<<2048, 256, 0, stream>>>(dst, deg);
    scan1<<<NB_NODE, 256, 0, stream>>>(deg, end_, partials);
    scan2<<<1, 512, 0, stream>>>(partials, NB_NODE);
    scan3<<<NB_NODE, 256, 0, stream>>>(deg, end_, cursor, partials);
    fill_adj_xcd<<<2048, 256, 0, stream>>>(src, dst, cursor, adj);

    // ---- fused layers ----
    fused_layer<F_IN, false><<<FL_BLOCKS, 256, 0, stream>>>(
        x, adj, end_, deg, W1_rel, b1_rel, W1_root, h1, nullptr, nullptr);
    fused_layer<F_HID, true><<<FL_BLOCKS, 256, 0, stream>>>(
        h1, adj, end_, deg, W2_rel, b2_rel, W2_root, nullptr, batch, sums);

    graph_counts<<<1, 256, 0, stream>>>(batch, counts);
    finalize<<<(N_GRAPHS * 64 + 255) / 256, 256, 0, stream>>>(sums, counts, out);
}

// Round 17
// 396.190 us; speedup vs baseline: 1.4036x; 1.4036x over previous
//
#include <hip/hip_runtime.h>

#define N_NODES 100000
#define N_EDGES 1600000
#define N_GRAPHS 256
#define F_IN 32
#define F_HID 64
#define F_OUT 64

#define FL_BLOCKS 25000         // 100000 waves = 1 wave per node (gather concurrency!)
#define P_WAVES 8192
#define P_NPW ((N_NODES + P_WAVES - 1) / P_WAVES)   // 13
#define NXCD 8
#define DPX ((N_NODES + NXCD - 1) / NXCD)

// ---------------- CSR build ----------------
__global__ __launch_bounds__(256) void histogram_xcd(const int* __restrict__ dst,
                                                     int* __restrict__ deg) {
    int xcd = blockIdx.x & (NXCD - 1);
    int sub = blockIdx.x >> 3;
    int nsub = gridDim.x >> 3;
    int d_lo = xcd * DPX;
    int d_hi = min(d_lo + DPX, N_NODES);
    for (int e = sub * blockDim.x + threadIdx.x; e < N_EDGES; e += nsub * blockDim.x) {
        int d = __builtin_nontemporal_load(dst + e);
        if (d >= d_lo && d < d_hi) atomicAdd(&deg[d], 1);
    }
}

__global__ void scan1(const int* __restrict__ deg, int* __restrict__ end_, int* __restrict__ partials) {
    __shared__ int s[256];
    int tid = threadIdx.x;
    int i = blockIdx.x * 256 + tid;
    int v = (i < N_NODES) ? deg[i] : 0;
    s[tid] = v;
    __syncthreads();
#pragma unroll
    for (int off = 1; off < 256; off <<= 1) {
        int t = 0;
        if (tid >= off) t = s[tid - off];
        __syncthreads();
        if (tid >= off) s[tid] += t;
        __syncthreads();
    }
    if (i < N_NODES) end_[i] = s[tid];
    if (tid == 255) partials[blockIdx.x] = s[255];
}

__global__ void scan2(int* __restrict__ partials, int nb) {
    __shared__ int s[512];
    int tid = threadIdx.x;
    int v = (tid < nb) ? partials[tid] : 0;
    s[tid] = v;
    __syncthreads();
#pragma unroll
    for (int off = 1; off < 512; off <<= 1) {
        int t = 0;
        if (tid >= off) t = s[tid - off];
        __syncthreads();
        if (tid >= off) s[tid] += t;
        __syncthreads();
    }
    int excl = (tid > 0) ? s[tid - 1] : 0;
    if (tid < nb) partials[tid] = excl;
}

__global__ void scan3(const int* __restrict__ deg, int* __restrict__ end_,
                      int* __restrict__ cursor, const int* __restrict__ partials) {
    int i = blockIdx.x * 256 + threadIdx.x;
    if (i < N_NODES) {
        int e = end_[i] + partials[blockIdx.x];
        end_[i] = e;
        cursor[i] = e - deg[i];
    }
}

__global__ __launch_bounds__(256) void fill_adj_xcd(const int* __restrict__ src,
                                                    const int* __restrict__ dst,
                                                    int* __restrict__ cursor,
                                                    int* __restrict__ adj) {
    int xcd = blockIdx.x & (NXCD - 1);
    int sub = blockIdx.x >> 3;
    int nsub = gridDim.x >> 3;
    int d_lo = xcd * DPX;
    int d_hi = min(d_lo + DPX, N_NODES);
    for (int e = sub * blockDim.x + threadIdx.x; e < N_EDGES; e += nsub * blockDim.x) {
        int d = __builtin_nontemporal_load(dst + e);
        if (d >= d_lo && d < d_hi) {
            int pos = atomicAdd(&cursor[d], 1);
            adj[pos] = __builtin_nontemporal_load(src + e);
        }
    }
}

// ------- fused gather+transform, ONE WAVE PER NODE (R16 math, R8 concurrency) -------
// Gather: lane=(r,q), float4 loads, xor-butterfly -> every lane holds full agg quad q.
// Transform: per k-quad broadcast from lane kq (8 shfl) + per-lane coalesced weight
// columns (L1-resident) + FMA. Writes hout row (coalesced 4B/lane).
template <int FIN>
__global__ __launch_bounds__(256) void fused_layer1w(
        const float* __restrict__ hin,
        const int* __restrict__ adj, const int* __restrict__ end_, const int* __restrict__ deg,
        const float* __restrict__ Wrel, const float* __restrict__ brel,
        const float* __restrict__ Wroot,
        float* __restrict__ hout) {
    constexpr int NQ = FIN / 4;       // 8 (FIN=32) or 16 (FIN=64)
    constexpr int R = 64 / NQ;        // 8 or 4
    const int lane = threadIdx.x & 63;
    const int node = blockIdx.x * 4 + (threadIdx.x >> 6);
    if (node >= N_NODES) return;
    const int q = lane & (NQ - 1);
    const int r = lane / NQ;
    const float4* h4 = (const float4*)hin;

    int e = end_[node];
    int d = deg[node];
    int s = e - d;
    float ax = 0.f, ay = 0.f, az = 0.f, aw = 0.f;
    for (int base = 0; base < d; base += 2 * R) {
        int i0 = base + r;
        int i1 = base + R + r;
        if (i0 < d) {
            int sn = adj[s + i0];
            float4 v = h4[(size_t)sn * NQ + q];
            ax += v.x; ay += v.y; az += v.z; aw += v.w;
        }
        if (i1 < d) {
            int sn = adj[s + i1];
            float4 v = h4[(size_t)sn * NQ + q];
            ax += v.x; ay += v.y; az += v.z; aw += v.w;
        }
    }
#pragma unroll
    for (int off = NQ; off < 64; off <<= 1) {
        ax += __shfl_xor(ax, off);
        ay += __shfl_xor(ay, off);
        az += __shfl_xor(az, off);
        aw += __shfl_xor(aw, off);
    }
    float4 xv = h4[(size_t)node * NQ + q];

    float o = brel[lane];
#pragma unroll
    for (int kq = 0; kq < NQ; ++kq) {
        float a0 = __shfl(ax, kq), a1 = __shfl(ay, kq);
        float a2 = __shfl(az, kq), a3 = __shfl(aw, kq);
        float x0 = __shfl(xv.x, kq), x1 = __shfl(xv.y, kq);
        float x2 = __shfl(xv.z, kq), x3 = __shfl(xv.w, kq);
        o += a0 * Wrel[(4 * kq + 0) * 64 + lane] + a1 * Wrel[(4 * kq + 1) * 64 + lane]
           + a2 * Wrel[(4 * kq + 2) * 64 + lane] + a3 * Wrel[(4 * kq + 3) * 64 + lane];
        o += x0 * Wroot[(4 * kq + 0) * 64 + lane] + x1 * Wroot[(4 * kq + 1) * 64 + lane]
           + x2 * Wroot[(4 * kq + 2) * 64 + lane] + x3 * Wroot[(4 * kq + 3) * 64 + lane];
    }
    hout[(size_t)node * 64 + lane] = tanhf(o);
}

// ------- pool pass: coalesced h2 stream + register psum, flush on graph change -------
__global__ __launch_bounds__(256) void pool_h2(const float* __restrict__ h2,
        const int* __restrict__ batch, float* __restrict__ sums) {
    int lane = threadIdx.x & 63;
    int wgid = __builtin_amdgcn_readfirstlane(blockIdx.x * 4 + (threadIdx.x >> 6));
    int n0 = wgid * P_NPW;
    if (n0 >= N_NODES) return;
    int n1 = min(n0 + P_NPW, N_NODES);

    float psum = 0.0f;
    int curg = batch[n0];
    for (int node = n0; node < n1; ++node) {
        float v = h2[(size_t)node * 64 + lane];
        int g = batch[node];
        if (g != curg) {
            atomicAdd(&sums[(size_t)curg * 64 + lane], psum);
            psum = 0.0f;
            curg = g;
        }
        psum += v;
    }
    atomicAdd(&sums[(size_t)curg * 64 + lane], psum);
}

__global__ void graph_counts(const int* __restrict__ batch, float* __restrict__ counts) {
    int g = threadIdx.x;
    if (g >= N_GRAPHS) return;
    int lo = 0, hi = N_NODES;
    while (lo < hi) { int mid = (lo + hi) >> 1; if (batch[mid] < g) lo = mid + 1; else hi = mid; }
    int start = lo;
    lo = 0; hi = N_NODES;
    while (lo < hi) { int mid = (lo + hi) >> 1; if (batch[mid] <= g) lo = mid + 1; else hi = mid; }
    counts[g] = (float)(lo - start);
}

__global__ void finalize(const float* __restrict__ sums,
                         const float* __restrict__ counts,
                         float* __restrict__ out) {
    int i = blockIdx.x * blockDim.x + threadIdx.x;
    if (i < N_GRAPHS * 64) {
        float c = counts[i >> 6];
        out[i] = sums[i] / fmaxf(c, 1.0f);
    }
}

extern "C" void kernel_launch(void* const* d_in, const int* in_sizes, int n_in,
                              void* d_out, int out_size, void* d_ws, size_t ws_size,
                              hipStream_t stream) {
    const float* x       = (const float*)d_in[0];
    const int*   ei      = (const int*)d_in[1];
    const int*   batch   = (const int*)d_in[2];
    const float* W1_rel  = (const float*)d_in[3];
    const float* b1_rel  = (const float*)d_in[4];
    const float* W1_root = (const float*)d_in[5];
    const float* W2_rel  = (const float*)d_in[6];
    const float* b2_rel  = (const float*)d_in[7];
    const float* W2_root = (const float*)d_in[8];
    float* out = (float*)d_out;

    const int* src = ei;
    const int* dst = ei + N_EDGES;

    // ---- workspace layout (bytes) ----
    char* ws = (char*)d_ws;
    int*   deg      = (int*)(ws + 0);                 // 400000
    float* sums     = (float*)(ws + 400000);          // 65536
    float* counts   = (float*)(ws + 465536);          // 1024
    // ---- zero boundary: 466560 ----
    int*   end_     = (int*)(ws + 466560);            // 400000
    int*   cursor   = (int*)(ws + 866560);            // 400000
    int*   partials = (int*)(ws + 1266560);           // 2048
    int*   adj      = (int*)(ws + 1268608);           // 6400000
    float* h1       = (float*)(ws + 7668608);         // 25600000
    float* h2       = (float*)(ws + 33268608);        // 25600000

    hipMemsetAsync(d_ws, 0, 466560, stream);

    // ---- CSR build ----
    const int NB_NODE = (N_NODES + 255) / 256;
    histogram_xcd<<<2048, 256, 0, stream>>>(dst, deg);
    scan1<<<NB_NODE, 256, 0, stream>>>(deg, end_, partials);
    scan2<<<1, 512, 0, stream>>>(partials, NB_NODE);
    scan3<<<NB_NODE, 256, 0, stream>>>(deg, end_, cursor, partials);
    fill_adj_xcd<<<2048, 256, 0, stream>>>(src, dst, cursor, adj);

    // ---- fused layers (1 wave/node) + pool ----
    fused_layer1w<F_IN><<<FL_BLOCKS, 256, 0, stream>>>(
        x, adj, end_, deg, W1_rel, b1_rel, W1_root, h1);
    fused_layer1w<F_HID><<<FL_BLOCKS, 256, 0, stream>>>(
        h1, adj, end_, deg, W2_rel, b2_rel, W2_root, h2);
    pool_h2<<<P_WAVES / 4, 256, 0, stream>>>(h2, batch, sums);

    graph_counts<<<1, 256, 0, stream>>>(batch, counts);
    finalize<<<(N_GRAPHS * 64 + 255) / 256, 256, 0, stream>>>(sums, counts, out);
}